// Round 11
// baseline (853.843 us; speedup 1.0000x reference)
//
#include <hip/hip_runtime.h>

// Greedy NMS: keep[i] = !any(keep[j] for j in knn[i] if j < i)
//
// Round-11: resident chained-chunk wavefront, 74 x 2048-row chunks.
// Round-10 model (validated): total ~= M*256B/(WCH*42GB/s)  [one-time row
// reload per block, overlapped WCH deep] + NCH*fixed(~4.7us). So:
//   - WCH 4 -> 16: reload term 229us -> ~57us, hidden under ~70us of slack.
//   - off-turn exl probing: on each progress tick with praw > b-WCH, probe
//     recorded window entries with j < praw*CHUNK vs the mirrored LDS bitmask.
//     On turn only chunk b-1's entries remain: mirror 64 words + <=24 LDS
//     probes + fixed-point + publish. No bulk memory on the critical path.
//   - ECAP=24 (window lambda~14, overflow ~0.5% -> per-row on-turn reload
//     fallback); ICAP=6; st back to u8 (int32 didn't reduce conflicts).
//
// Output encoding (validated round 4): INT32.
//   d_out[0..M)        : kept flags, 1 / 0
//   d_out[M..M+M*64)   : kept_knn, idx or 150000 (tail doubles as bitmask
//                        scratch, owned by block 73 which never publishes)
// d_ws[0..3]: progress counter (zeroed by init kernel each call)

#define M_ROWS 150000
#define KNN    64
#define BLK    1024
#define QRT    2
#define CHUNK  (BLK * QRT)                        // 2048
#define NCH    ((M_ROWS + CHUNK - 1) / CHUNK)     // 74
#define ICAP   6
#define ECAP   24
#define WCH    16                                 // exl window, chunks
#define LMW    (((NCH - 1) * CHUNK) / 32)         // 4672 u32 bitmask words
#define OUT_INTS (M_ROWS + M_ROWS * KNN)
#define BMG_OFF  (OUT_INTS - LMW)

__global__ void init_ws_kernel(unsigned int* progress) {
  if (threadIdx.x == 0) *progress = 0u;
}

__device__ __forceinline__ unsigned int bm_load(const unsigned int* p) {
  return __hip_atomic_load(p, __ATOMIC_RELAXED, __HIP_MEMORY_SCOPE_AGENT);
}

// reload a row and probe preds j in [lo, hi) against the LDS bitmask
__device__ __forceinline__ bool probe_reload(const int* __restrict__ rp,
                                             const unsigned int* lm,
                                             int lo, int hi) {
  bool s = false;
#pragma unroll
  for (int u = 0; u < 16; ++u) {
    int4 d = ((const int4*)rp)[u];
    int js[4] = {d.x, d.y, d.z, d.w};
#pragma unroll
    for (int m = 0; m < 4; ++m) {
      int j = js[m];
      if (j >= lo && j < hi && ((lm[j >> 5] >> (j & 31)) & 1u)) s = true;
    }
  }
  return s;
}

__global__ __launch_bounds__(BLK) void nms_chain_kernel(
    const int* __restrict__ knn,
    int* __restrict__ out,
    unsigned int* __restrict__ progress)
{
  const int b    = blockIdx.x;
  const int t    = threadIdx.x;
  const int base = b * CHUNK;
  const int winb = (b > WCH) ? (base - WCH * CHUNK) : 0;   // exl window base

  unsigned int* bmg = (unsigned int*)out + BMG_OFF;
  unsigned long long* bmg64 = (unsigned long long*)bmg;

  __shared__ unsigned char      st[CHUNK];        // 0 unk, 1 kept, 2 supp
  __shared__ unsigned short     il[CHUNK][ICAP];  // intra-chunk pred offsets
  __shared__ unsigned short     exl[CHUNK][ECAP]; // window pred offs (j - winb)
  __shared__ unsigned int       lm[LMW];          // mirrored keep bits
  __shared__ unsigned long long bw[QRT][BLK / 64];
  __shared__ unsigned int       prog_sh[2];

  int  rowq[QRT];
  bool vq[QRT], ovf[QRT], eovf[QRT], supp[QRT];
  int  ic[QRT], ec[QRT];

#pragma unroll
  for (int q = 0; q < QRT; ++q) {
    rowq[q] = base + q * BLK + t;
    vq[q]   = rowq[q] < M_ROWS;
    ic[q] = ec[q] = 0;
    ovf[q] = eovf[q] = supp[q] = false;
  }

  // ---- classification: intra-chunk + static-window pred lists ----
#pragma unroll
  for (int q = 0; q < QRT; ++q) {
    if (!vq[q]) continue;
    const int o   = q * BLK + t;
    const int row = rowq[q];
    const int* rp = knn + (long long)row * KNN;
#pragma unroll
    for (int u = 0; u < 16; ++u) {
      int4 d = ((const int4*)rp)[u];
      int js[4] = {d.x, d.y, d.z, d.w};
#pragma unroll
      for (int m = 0; m < 4; ++m) {
        int j = js[m];
        if (j < row) {                            // strict <: ref semantics
          if (j >= base) {
            if (ic[q] < ICAP) il[o][ic[q]] = (unsigned short)(j - base);
            ++ic[q];
          } else if (j >= winb) {
            if (ec[q] < ECAP) exl[o][ec[q]] = (unsigned short)(j - winb);
            ++ec[q];
          }
          // j < winb: covered by the single forced reload pass
        }
      }
    }
  }
#pragma unroll
  for (int q = 0; q < QRT; ++q) {
    ovf[q]  = ic[q] > ICAP; if (ovf[q])  ic[q] = ICAP;
    eovf[q] = ec[q] > ECAP; if (eovf[q]) ec[q] = ECAP;
  }

  // ---- wait loop: mirror + off-turn window probing + one forced reload ----
  bool reloaded = (b <= WCH);                     // small b: window covers all
  int  rel_lim  = 0;                              // reload probed [0, rel_lim)
  int  p_done   = 0;                              // exl probed vs lim p_done*CHUNK
  int  wcop     = 0;
  for (int spin = 0; ; ++spin) {
    const int slot = spin & 1;
    if (t == 0)
      prog_sh[slot] = __hip_atomic_load(progress, __ATOMIC_RELAXED,
                                        __HIP_MEMORY_SCOPE_AGENT);
    __syncthreads();                              // slot reuse safe: 1 barrier apart
    const int praw = (int)prog_sh[slot];
    if (praw >= b) {                              // our turn
      const int wt = b * (CHUNK / 32);            // final lm catch-up (usually 64 words)
      for (int w = wcop + t; w < wt; w += BLK) lm[w] = bm_load(&bmg[w]);
      wcop = wt;
      __syncthreads();                            // lm visible
      break;
    }
    if (!reloaded && praw >= b - WCH) {           // one forced pass, ~WCH steps slack
      const int wt = praw * (CHUNK / 32);
      for (int w = wcop + t; w < wt; w += BLK) lm[w] = bm_load(&bmg[w]);
      wcop = wt;
      __syncthreads();
      const int lim = praw * CHUNK;
#pragma unroll
      for (int q = 0; q < QRT; ++q)
        if (vq[q] && !supp[q])
          supp[q] = probe_reload(knn + (long long)rowq[q] * KNN, lm, 0, lim);
      rel_lim  = lim;
      p_done   = praw;
      reloaded = true;
    } else if (reloaded && praw > p_done && praw > b - WCH) {
      // off-turn: mirror new chunks, probe recorded window entries
      const int wt = praw * (CHUNK / 32);
      for (int w = wcop + t; w < wt; w += BLK) lm[w] = bm_load(&bmg[w]);
      wcop = wt;
      __syncthreads();
      const int lim = praw * CHUNK;
#pragma unroll
      for (int q = 0; q < QRT; ++q) {
        if (!vq[q] || supp[q]) continue;
        const int o = q * BLK + t;
        const int n = ec[q];
        for (int x = 0; x < n; ++x) {
          int j = winb + (int)exl[o][x];
          if (j < lim && ((lm[j >> 5] >> (j & 31)) & 1u)) { supp[q] = true; break; }
        }
      }
      p_done = praw;
    }
    if (spin > (1 << 22)) break;                  // safety valve
    __builtin_amdgcn_s_sleep(1);
  }

  // ---- on-turn: rare catch-up + last-chunk LDS probes + overflow fallback ----
  if (b > WCH && rel_lim < winb) {                // missed forced pass (rare)
#pragma unroll
    for (int q = 0; q < QRT; ++q)
      if (vq[q] && !supp[q])
        supp[q] = probe_reload(knn + (long long)rowq[q] * KNN, lm, rel_lim, winb);
  }
  if (b > 0) {
#pragma unroll
    for (int q = 0; q < QRT; ++q) {
      if (!vq[q] || supp[q]) continue;
      const int o = q * BLK + t;
      const int n = ec[q];
      for (int x = 0; x < n; ++x) {               // only chunk b-1 bits are new
        int j = winb + (int)exl[o][x];
        if ((lm[j >> 5] >> (j & 31)) & 1u) { supp[q] = true; break; }
      }
      if (!supp[q] && eovf[q])                    // dropped entries (~0.5% rows)
        supp[q] = probe_reload(knn + (long long)rowq[q] * KNN, lm, winb, base);
    }
  }

  // ---- intra-chunk monotone fixed-point (validated rounds 4-10) ----
#pragma unroll
  for (int q = 0; q < QRT; ++q) {
    const int o = q * BLK + t;
    st[o] = (!vq[q] || supp[q]) ? (unsigned char)2
          : ((ic[q] == 0 && !ovf[q]) ? (unsigned char)1 : (unsigned char)0);
  }
  __syncthreads();

  for (int it = 0; it < CHUNK; ++it) {
    bool un = false;
#pragma unroll
    for (int s = 0; s < 2; ++s) {                 // monotone: stale reads safe
      un = false;
#pragma unroll
      for (int q = 0; q < QRT; ++q) {
        const int o = q * BLK + t;
        if (st[o] == 0) {
          bool anyK = false, allD = true;
          if (!ovf[q]) {
            for (int x = 0; x < ic[q]; ++x) {
              unsigned char v = st[il[o][x]];
              anyK |= (v == 1); allD &= (v != 0);
            }
          } else {                                // rare: rescan from global
            const int row = rowq[q];
            const int* rp = knn + (long long)row * KNN;
#pragma unroll
            for (int k = 0; k < KNN; ++k) {
              int j = rp[k];
              if (j >= base && j < row) {
                unsigned char v = st[j - base];
                anyK |= (v == 1); allD &= (v != 0);
              }
            }
          }
          if (anyK) st[o] = 2; else if (allD) st[o] = 1;
          if (st[o] == 0) un = true;
        }
      }
    }
    if (__syncthreads_count((int)un) == 0) break;
  }

  // ---- publish: ballots -> LDS -> wave 0 stores + release ----
  bool kq[QRT];
#pragma unroll
  for (int q = 0; q < QRT; ++q)
    kq[q] = vq[q] && (st[q * BLK + t] == 1);

#pragma unroll
  for (int q = 0; q < QRT; ++q) {
    unsigned long long ba = __ballot(kq[q]);      // rows base+q*1024+w*64+lane
    if ((t & 63) == 0) bw[q][t >> 6] = ba;
  }
  __syncthreads();
  if (b < NCH - 1 && t < CHUNK / 64) {            // wave 0: 32 u64 words
    __hip_atomic_store(&bmg64[b * (CHUNK / 64) + t], bw[t >> 4][t & 15],
                       __ATOMIC_RELAXED, __HIP_MEMORY_SCOPE_AGENT);
  }
  if (t == 0)                                     // same wave: stores precede release
    __hip_atomic_store(progress, (unsigned int)(b + 1),
                       __ATOMIC_RELEASE, __HIP_MEMORY_SCOPE_AGENT);

  // ---- outputs (off the chain; block 73's knn overwrites dead bitmask) ----
#pragma unroll
  for (int q = 0; q < QRT; ++q)
    if (vq[q]) out[rowq[q]] = kq[q] ? 1 : 0;

#pragma unroll
  for (int q = 0; q < QRT; ++q) {
    if (!vq[q]) continue;
    const int row = rowq[q];
    const int* rp = knn + (long long)row * KNN;
    int* orow = out + M_ROWS + (long long)row * KNN;
    const bool k = kq[q];
#pragma unroll
    for (int u = 0; u < 16; ++u) {
      int4 d = ((const int4*)rp)[u];
      int4 o4;
      o4.x = k ? d.x : M_ROWS;
      o4.y = k ? d.y : M_ROWS;
      o4.z = k ? d.z : M_ROWS;
      o4.w = k ? d.w : M_ROWS;
      ((int4*)orow)[u] = o4;
    }
  }
}

extern "C" void kernel_launch(void* const* d_in, const int* in_sizes, int n_in,
                              void* d_out, int out_size, void* d_ws, size_t ws_size,
                              hipStream_t stream) {
  const int* knn = (const int*)d_in[1];
  int* out = (int*)d_out;
  unsigned int* progress = (unsigned int*)d_ws;

  init_ws_kernel<<<1, 64, 0, stream>>>(progress);
  nms_chain_kernel<<<NCH, BLK, 0, stream>>>(knn, out, progress);
}

// Round 12
// 597.659 us; speedup vs baseline: 1.4286x; 1.4286x over previous
//
#include <hip/hip_runtime.h>

// Greedy NMS: keep[i] = !any(keep[j] for j in knn[i] if j < i)
//
// Round-12: R9 macro-structure (74 x 2048 chunks, WCH=4, one forced reload),
// with the head-block on-turn path stripped (R9/R10 fit: total ~= M x 3.9ns/row,
// all head-block serialized work):
//   - TRANSPOSED LDS lists il[ICAP][CHUNK], exl[ECAP][CHUNK]: lane-consecutive
//     -> conflict-free (old [row][slot] layout = 4-8-way bank conflicts).
//   - wave-0-only polling: 2 block barriers total in the wait path (not one
//     per poll iteration); other waves park at the barrier.
//   - flag-based fixed-point convergence check; 2 monotone sweeps/iter.
//   - on-turn exl probes filtered to j >= phase-1 reload limit.
//   - R11 lesson kept: NO per-tick off-turn work.
//
// Output encoding (validated round 4): INT32.
//   d_out[0..M)        : kept flags, 1 / 0
//   d_out[M..M+M*64)   : kept_knn, idx or 150000 (tail doubles as bitmask
//                        scratch, owned by block 73 which never publishes)
// d_ws[0..3]: progress counter (zeroed by init kernel each call)

#define M_ROWS 150000
#define KNN    64
#define BLK    1024
#define QRT    2
#define CHUNK  (BLK * QRT)                        // 2048
#define NCH    ((M_ROWS + CHUNK - 1) / CHUNK)     // 74
#define ICAP   6
#define ECAP   12
#define WCH    4                                  // exl window, chunks
#define LMW    (((NCH - 1) * CHUNK) / 32)         // 4672 u32 bitmask words
#define OUT_INTS (M_ROWS + M_ROWS * KNN)
#define BMG_OFF  (OUT_INTS - LMW)

__global__ void init_ws_kernel(unsigned int* progress) {
  if (threadIdx.x == 0) *progress = 0u;
}

__device__ __forceinline__ unsigned int bm_load(const unsigned int* p) {
  return __hip_atomic_load(p, __ATOMIC_RELAXED, __HIP_MEMORY_SCOPE_AGENT);
}

// reload a row and probe preds j in [lo, hi) against the LDS bitmask
__device__ __forceinline__ bool probe_reload(const int* __restrict__ rp,
                                             const unsigned int* lm,
                                             int lo, int hi) {
  bool s = false;
#pragma unroll
  for (int u = 0; u < 16; ++u) {
    int4 d = ((const int4*)rp)[u];
    int js[4] = {d.x, d.y, d.z, d.w};
#pragma unroll
    for (int m = 0; m < 4; ++m) {
      int j = js[m];
      if (j >= lo && j < hi && ((lm[j >> 5] >> (j & 31)) & 1u)) s = true;
    }
  }
  return s;
}

__global__ __launch_bounds__(BLK) void nms_chain_kernel(
    const int* __restrict__ knn,
    int* __restrict__ out,
    unsigned int* __restrict__ progress)
{
  const int b    = blockIdx.x;
  const int t    = threadIdx.x;
  const int base = b * CHUNK;
  const int winb = (b > WCH) ? (base - WCH * CHUNK) : 0;   // exl window base

  unsigned int* bmg = (unsigned int*)out + BMG_OFF;
  unsigned long long* bmg64 = (unsigned long long*)bmg;

  __shared__ unsigned char      st[CHUNK];        // 0 unk, 1 kept, 2 supp
  __shared__ unsigned short     il[ICAP][CHUNK];  // TRANSPOSED: conflict-free
  __shared__ unsigned short     exl[ECAP][CHUNK]; // TRANSPOSED: conflict-free
  __shared__ unsigned int       lm[LMW];          // mirrored keep bits
  __shared__ unsigned long long bw[QRT][BLK / 64];
  __shared__ unsigned int       sh_p;
  __shared__ int                chg;

  int  rowq[QRT];
  bool vq[QRT], ovf[QRT], eovf[QRT], supp[QRT];
  int  ic[QRT], ec[QRT];

#pragma unroll
  for (int q = 0; q < QRT; ++q) {
    rowq[q] = base + q * BLK + t;
    vq[q]   = rowq[q] < M_ROWS;
    ic[q] = ec[q] = 0;
    ovf[q] = eovf[q] = supp[q] = false;
  }

  // ---- classification: intra-chunk + static-window pred lists ----
#pragma unroll
  for (int q = 0; q < QRT; ++q) {
    if (!vq[q]) continue;
    const int o   = q * BLK + t;
    const int row = rowq[q];
    const int* rp = knn + (long long)row * KNN;
#pragma unroll
    for (int u = 0; u < 16; ++u) {
      int4 d = ((const int4*)rp)[u];
      int js[4] = {d.x, d.y, d.z, d.w};
#pragma unroll
      for (int m = 0; m < 4; ++m) {
        int j = js[m];
        if (j < row) {                            // strict <: ref semantics
          if (j >= base) {
            if (ic[q] < ICAP) il[ic[q]][o] = (unsigned short)(j - base);
            ++ic[q];
          } else if (j >= winb) {
            if (ec[q] < ECAP) exl[ec[q]][o] = (unsigned short)(j - winb);
            ++ec[q];
          }
          // j < winb: covered by the phase-1 reload probe
        }
      }
    }
  }
#pragma unroll
  for (int q = 0; q < QRT; ++q) {
    ovf[q]  = ic[q] > ICAP; if (ovf[q])  ic[q] = ICAP;
    eovf[q] = ec[q] > ECAP; if (eovf[q]) ec[q] = ECAP;
  }

  // ---- wait path: wave-0 polling, 2 block barriers total ----
  int praw1 = 0, wcop = 0;
  if (b > WCH) {
    // phase 1: trigger the single forced reload ~WCH steps early
    if (t < 64) {
      int pr = 0;
      for (int spin = 0; spin < (1 << 22); ++spin) {
        pr = (int)__hip_atomic_load(progress, __ATOMIC_RELAXED,
                                    __HIP_MEMORY_SCOPE_AGENT);
        if (pr >= b - WCH) break;
        __builtin_amdgcn_s_sleep(2);
      }
      if (t == 0) sh_p = (unsigned int)pr;
    }
    __syncthreads();                              // barrier 1: sh_p visible
    praw1 = (int)sh_p; if (praw1 > b) praw1 = b;
    const int wt = praw1 * (CHUNK / 32);
    for (int w = t; w < wt; w += BLK) lm[w] = bm_load(&bmg[w]);
    wcop = wt;
    __syncthreads();                              // lm visible
    const int lim = praw1 * CHUNK;
#pragma unroll
    for (int q = 0; q < QRT; ++q)
      if (vq[q] && !supp[q])
        supp[q] = probe_reload(knn + (long long)rowq[q] * KNN, lm, 0, lim);
  }
  if (b > 0 && praw1 < b) {
    // phase 2: wait for our turn (wave 0 spins; others park at the barrier)
    if (t < 64) {
      for (int spin = 0; spin < (1 << 22); ++spin) {
        int pr = (int)__hip_atomic_load(progress, __ATOMIC_RELAXED,
                                        __HIP_MEMORY_SCOPE_AGENT);
        if (pr >= b) break;
        __builtin_amdgcn_s_sleep(1);
      }
    }
    __syncthreads();                              // barrier 2: turn detected
  }
  if (b > 0) {
    const int wt = b * (CHUNK / 32);              // final mirror catch-up
    for (int w = wcop + t; w < wt; w += BLK) lm[w] = bm_load(&bmg[w]);
    __syncthreads();                              // lm visible
    // window probes: only entries >= phase-1 limit are new (older covered)
    const int pr1lim = praw1 * CHUNK;
#pragma unroll
    for (int q = 0; q < QRT; ++q) {
      if (!vq[q] || supp[q]) continue;
      const int o = q * BLK + t;
      const int n = ec[q];
      for (int x = 0; x < n; ++x) {
        int j = winb + (int)exl[x][o];
        if (j >= pr1lim && ((lm[j >> 5] >> (j & 31)) & 1u)) { supp[q] = true; break; }
      }
      if (!supp[q] && eovf[q])                    // dropped entries (rare)
        supp[q] = probe_reload(knn + (long long)rowq[q] * KNN, lm, winb, base);
    }
  }

  // ---- intra-chunk monotone fixed-point (flag-based convergence) ----
#pragma unroll
  for (int q = 0; q < QRT; ++q) {
    const int o = q * BLK + t;
    st[o] = (!vq[q] || supp[q]) ? (unsigned char)2
          : ((ic[q] == 0 && !ovf[q]) ? (unsigned char)1 : (unsigned char)0);
  }
  __syncthreads();

  for (int it = 0; it < CHUNK; ++it) {
    if (t == 0) chg = 0;
    __syncthreads();                              // reset visible
    bool un = false;
#pragma unroll
    for (int s = 0; s < 2; ++s) {                 // monotone: stale reads safe
      un = false;
#pragma unroll
      for (int q = 0; q < QRT; ++q) {
        const int o = q * BLK + t;
        if (st[o] == 0) {
          bool anyK = false, allD = true;
          if (!ovf[q]) {
            for (int x = 0; x < ic[q]; ++x) {
              unsigned char v = st[il[x][o]];
              anyK |= (v == 1); allD &= (v != 0);
            }
          } else {                                // rare: rescan from global
            const int row = rowq[q];
            const int* rp = knn + (long long)row * KNN;
#pragma unroll
            for (int k = 0; k < KNN; ++k) {
              int j = rp[k];
              if (j >= base && j < row) {
                unsigned char v = st[j - base];
                anyK |= (v == 1); allD &= (v != 0);
              }
            }
          }
          if (anyK) st[o] = 2; else if (allD) st[o] = 1;
          if (st[o] == 0) un = true;
        }
      }
    }
    if (un) chg = 1;                              // benign race
    __syncthreads();                              // chg + st visible
    if (chg == 0) break;
  }

  // ---- publish: ballots -> LDS -> wave 0 stores + release ----
  bool kq[QRT];
#pragma unroll
  for (int q = 0; q < QRT; ++q)
    kq[q] = vq[q] && (st[q * BLK + t] == 1);

#pragma unroll
  for (int q = 0; q < QRT; ++q) {
    unsigned long long ba = __ballot(kq[q]);      // rows base+q*1024+w*64+lane
    if ((t & 63) == 0) bw[q][t >> 6] = ba;
  }
  __syncthreads();
  if (b < NCH - 1 && t < CHUNK / 64) {            // wave 0: 32 u64 words
    __hip_atomic_store(&bmg64[b * (CHUNK / 64) + t], bw[t >> 4][t & 15],
                       __ATOMIC_RELAXED, __HIP_MEMORY_SCOPE_AGENT);
  }
  if (t == 0)                                     // same wave: stores precede release
    __hip_atomic_store(progress, (unsigned int)(b + 1),
                       __ATOMIC_RELEASE, __HIP_MEMORY_SCOPE_AGENT);

  // ---- outputs (off the chain; block 73's knn overwrites dead bitmask) ----
#pragma unroll
  for (int q = 0; q < QRT; ++q)
    if (vq[q]) out[rowq[q]] = kq[q] ? 1 : 0;

#pragma unroll
  for (int q = 0; q < QRT; ++q) {
    if (!vq[q]) continue;
    const int row = rowq[q];
    const int* rp = knn + (long long)row * KNN;
    int* orow = out + M_ROWS + (long long)row * KNN;
    const bool k = kq[q];
#pragma unroll
    for (int u = 0; u < 16; ++u) {
      int4 d = ((const int4*)rp)[u];
      int4 o4;
      o4.x = k ? d.x : M_ROWS;
      o4.y = k ? d.y : M_ROWS;
      o4.z = k ? d.z : M_ROWS;
      o4.w = k ? d.w : M_ROWS;
      ((int4*)orow)[u] = o4;
    }
  }
}

extern "C" void kernel_launch(void* const* d_in, const int* in_sizes, int n_in,
                              void* d_out, int out_size, void* d_ws, size_t ws_size,
                              hipStream_t stream) {
  const int* knn = (const int*)d_in[1];
  int* out = (int*)d_out;
  unsigned int* progress = (unsigned int*)d_ws;

  init_ws_kernel<<<1, 64, 0, stream>>>(progress);
  nms_chain_kernel<<<NCH, BLK, 0, stream>>>(knn, out, progress);
}